// Round 1
// baseline (159.779 us; speedup 1.0000x reference)
//
#include <hip/hip_runtime.h>
#include <math.h>

#define B_DIM 16
#define T_DIM 4096
#define NSRC 3
#define D_DIM 512
#define DC_PER_ROW (D_DIM / 4)        // 128 float4 chunks per (t,s) row
#define BLOCKS_PER_B 128
#define T_PER_BLOCK (T_DIM / BLOCKS_PER_B)  // 32

__device__ __forceinline__ float dot4(float4 a, float4 b) {
    float r = a.x * b.x;
    r = fmaf(a.y, b.y, r);
    r = fmaf(a.z, b.z, r);
    r = fmaf(a.w, b.w, r);
    return r;
}

// Accumulates per-b partials: ws[b*15 + {0..2:pn, 3..5:gn, 6..14:cross[s][r]}]
__global__ __launch_bounds__(256) void minloss_partial(
        const float* __restrict__ P, const float* __restrict__ G,
        float* __restrict__ ws) {
    const int bid   = blockIdx.x;
    const int b     = bid >> 7;            // / BLOCKS_PER_B
    const int chunk = bid & (BLOCKS_PER_B - 1);
    const int tid   = threadIdx.x;
    const int dc    = tid & (DC_PER_ROW - 1);   // float4 index within d
    const int tp    = tid >> 7;                  // 0 or 1: t parity

    const size_t b_off = (size_t)b * T_DIM * NSRC * DC_PER_ROW;
    const float4* __restrict__ Pb = (const float4*)P + b_off;
    const float4* __restrict__ Gb = (const float4*)G + b_off;

    float acc[15];
#pragma unroll
    for (int k = 0; k < 15; ++k) acc[k] = 0.0f;

    const int t0 = chunk * T_PER_BLOCK;
    for (int t = t0 + tp; t < t0 + T_PER_BLOCK; t += 2) {
        const float4* __restrict__ Pr = Pb + (size_t)t * NSRC * DC_PER_ROW;
        const float4* __restrict__ Gr = Gb + (size_t)t * NSRC * DC_PER_ROW;
        float4 p0 = Pr[dc];
        float4 p1 = Pr[DC_PER_ROW + dc];
        float4 p2 = Pr[2 * DC_PER_ROW + dc];
        float4 g0 = Gr[dc];
        float4 g1 = Gr[DC_PER_ROW + dc];
        float4 g2 = Gr[2 * DC_PER_ROW + dc];

        acc[0] += dot4(p0, p0);
        acc[1] += dot4(p1, p1);
        acc[2] += dot4(p2, p2);
        acc[3] += dot4(g0, g0);
        acc[4] += dot4(g1, g1);
        acc[5] += dot4(g2, g2);
        acc[6]  += dot4(p0, g0);
        acc[7]  += dot4(p0, g1);
        acc[8]  += dot4(p0, g2);
        acc[9]  += dot4(p1, g0);
        acc[10] += dot4(p1, g1);
        acc[11] += dot4(p1, g2);
        acc[12] += dot4(p2, g0);
        acc[13] += dot4(p2, g1);
        acc[14] += dot4(p2, g2);
    }

    // wave-level reduce (wave = 64 lanes)
#pragma unroll
    for (int k = 0; k < 15; ++k) {
        float v = acc[k];
#pragma unroll
        for (int off = 32; off > 0; off >>= 1)
            v += __shfl_down(v, off);
        acc[k] = v;
    }

    __shared__ float sm[4][15];
    const int wid  = tid >> 6;
    const int lane = tid & 63;
    if (lane == 0) {
#pragma unroll
        for (int k = 0; k < 15; ++k) sm[wid][k] = acc[k];
    }
    __syncthreads();
    if (tid < 15) {
        float v = sm[0][tid] + sm[1][tid] + sm[2][tid] + sm[3][tid];
        atomicAdd(&ws[b * 15 + tid], v);
    }
}

__global__ void minloss_finalize(const float* __restrict__ ws,
                                 float* __restrict__ out) {
    if (threadIdx.x != 0 || blockIdx.x != 0) return;
    const int perms[6][3] = {{0,1,2},{0,2,1},{1,0,2},{1,2,0},{2,0,1},{2,1,0}};
    float accp[6] = {0.f, 0.f, 0.f, 0.f, 0.f, 0.f};
    for (int b = 0; b < B_DIM; ++b) {
        const float* w = ws + b * 15;
        float D[3][3];
#pragma unroll
        for (int s = 0; s < 3; ++s)
#pragma unroll
            for (int r = 0; r < 3; ++r) {
                float v = w[s] + w[3 + r] - 2.0f * w[6 + s * 3 + r];
                D[s][r] = sqrtf(fmaxf(v, 0.0f));
            }
#pragma unroll
        for (int p = 0; p < 6; ++p) {
            float su = (D[0][perms[p][0]] + D[1][perms[p][1]] +
                        D[2][perms[p][2]]) * (1.0f / 3.0f);
            accp[p] += fabsf(su);
        }
    }
    float mn = 3.0e38f;
#pragma unroll
    for (int p = 0; p < 6; ++p) {
        float loss = accp[p] * (1.0f / (float)B_DIM);
        mn = fminf(mn, loss);
    }
    out[0] = logf(mn);
}

extern "C" void kernel_launch(void* const* d_in, const int* in_sizes, int n_in,
                              void* d_out, int out_size, void* d_ws, size_t ws_size,
                              hipStream_t stream) {
    const float* P = (const float*)d_in[0];
    const float* G = (const float*)d_in[1];
    float* out = (float*)d_out;
    float* ws  = (float*)d_ws;

    hipMemsetAsync(ws, 0, B_DIM * 15 * sizeof(float), stream);
    minloss_partial<<<B_DIM * BLOCKS_PER_B, 256, 0, stream>>>(P, G, ws);
    minloss_finalize<<<1, 64, 0, stream>>>(ws, out);
}

// Round 2
// 133.591 us; speedup vs baseline: 1.1960x; 1.1960x over previous
//
#include <hip/hip_runtime.h>
#include <math.h>

#define B_DIM 16
#define T_DIM 4096
#define NSRC 3
#define D_DIM 512
#define DC_PER_ROW (D_DIM / 4)        // 128 float4 chunks per (t,s) row
#define BLOCKS_PER_B 128
#define T_PER_BLOCK (T_DIM / BLOCKS_PER_B)  // 32

typedef float f4 __attribute__((ext_vector_type(4)));

__device__ __forceinline__ float dot4(f4 a, f4 b) {
    float r = a.x * b.x;
    r = fmaf(a.y, b.y, r);
    r = fmaf(a.z, b.z, r);
    r = fmaf(a.w, b.w, r);
    return r;
}

// Each block writes its own 15-float partial slot:
// ws[(b*BLOCKS_PER_B + chunk)*15 + {0..2:pn, 3..5:gn, 6..14:cross[s][r]}]
__global__ __launch_bounds__(256) void minloss_partial(
        const float* __restrict__ P, const float* __restrict__ G,
        float* __restrict__ ws) {
    const int bid   = blockIdx.x;
    const int b     = bid >> 7;            // / BLOCKS_PER_B
    const int chunk = bid & (BLOCKS_PER_B - 1);
    const int tid   = threadIdx.x;
    const int dc    = tid & (DC_PER_ROW - 1);   // float4 index within d
    const int tp    = tid >> 7;                  // 0 or 1: t parity

    const size_t b_off = (size_t)b * T_DIM * NSRC * DC_PER_ROW;
    const f4* __restrict__ Pb = (const f4*)P + b_off;
    const f4* __restrict__ Gb = (const f4*)G + b_off;

    float acc[15];
#pragma unroll
    for (int k = 0; k < 15; ++k) acc[k] = 0.0f;

    const int t0 = chunk * T_PER_BLOCK;
    // unroll x2: rows t and t+2 each iteration; tp covers even/odd
    for (int t = t0 + tp; t < t0 + T_PER_BLOCK; t += 4) {
        const f4* __restrict__ Pr0 = Pb + (size_t)t * NSRC * DC_PER_ROW;
        const f4* __restrict__ Gr0 = Gb + (size_t)t * NSRC * DC_PER_ROW;
        const f4* __restrict__ Pr1 = Pr0 + 2 * NSRC * DC_PER_ROW;
        const f4* __restrict__ Gr1 = Gr0 + 2 * NSRC * DC_PER_ROW;

        f4 p0 = __builtin_nontemporal_load(Pr0 + dc);
        f4 p1 = __builtin_nontemporal_load(Pr0 + DC_PER_ROW + dc);
        f4 p2 = __builtin_nontemporal_load(Pr0 + 2 * DC_PER_ROW + dc);
        f4 g0 = __builtin_nontemporal_load(Gr0 + dc);
        f4 g1 = __builtin_nontemporal_load(Gr0 + DC_PER_ROW + dc);
        f4 g2 = __builtin_nontemporal_load(Gr0 + 2 * DC_PER_ROW + dc);
        f4 q0 = __builtin_nontemporal_load(Pr1 + dc);
        f4 q1 = __builtin_nontemporal_load(Pr1 + DC_PER_ROW + dc);
        f4 q2 = __builtin_nontemporal_load(Pr1 + 2 * DC_PER_ROW + dc);
        f4 h0 = __builtin_nontemporal_load(Gr1 + dc);
        f4 h1 = __builtin_nontemporal_load(Gr1 + DC_PER_ROW + dc);
        f4 h2 = __builtin_nontemporal_load(Gr1 + 2 * DC_PER_ROW + dc);

        acc[0] += dot4(p0, p0) + dot4(q0, q0);
        acc[1] += dot4(p1, p1) + dot4(q1, q1);
        acc[2] += dot4(p2, p2) + dot4(q2, q2);
        acc[3] += dot4(g0, g0) + dot4(h0, h0);
        acc[4] += dot4(g1, g1) + dot4(h1, h1);
        acc[5] += dot4(g2, g2) + dot4(h2, h2);
        acc[6]  += dot4(p0, g0) + dot4(q0, h0);
        acc[7]  += dot4(p0, g1) + dot4(q0, h1);
        acc[8]  += dot4(p0, g2) + dot4(q0, h2);
        acc[9]  += dot4(p1, g0) + dot4(q1, h0);
        acc[10] += dot4(p1, g1) + dot4(q1, h1);
        acc[11] += dot4(p1, g2) + dot4(q1, h2);
        acc[12] += dot4(p2, g0) + dot4(q2, h0);
        acc[13] += dot4(p2, g1) + dot4(q2, h1);
        acc[14] += dot4(p2, g2) + dot4(q2, h2);
    }

    // wave-level reduce (wave = 64 lanes)
#pragma unroll
    for (int k = 0; k < 15; ++k) {
        float v = acc[k];
#pragma unroll
        for (int off = 32; off > 0; off >>= 1)
            v += __shfl_down(v, off);
        acc[k] = v;
    }

    __shared__ float sm[4][15];
    const int wid  = tid >> 6;
    const int lane = tid & 63;
    if (lane == 0) {
#pragma unroll
        for (int k = 0; k < 15; ++k) sm[wid][k] = acc[k];
    }
    __syncthreads();
    if (tid < 15) {
        ws[bid * 15 + tid] = sm[0][tid] + sm[1][tid] + sm[2][tid] + sm[3][tid];
    }
}

__global__ void minloss_finalize(const float* __restrict__ ws,
                                 float* __restrict__ out) {
    __shared__ float sm[B_DIM][15];
    const int tid = threadIdx.x;
    if (tid < B_DIM * 15) {
        const int b = tid / 15;
        const int k = tid % 15;
        float v = 0.0f;
        for (int c = 0; c < BLOCKS_PER_B; ++c)
            v += ws[(b * BLOCKS_PER_B + c) * 15 + k];
        sm[b][k] = v;
    }
    __syncthreads();
    if (tid == 0) {
        const int perms[6][3] = {{0,1,2},{0,2,1},{1,0,2},{1,2,0},{2,0,1},{2,1,0}};
        float accp[6] = {0.f, 0.f, 0.f, 0.f, 0.f, 0.f};
        for (int b = 0; b < B_DIM; ++b) {
            const float* w = sm[b];
            float D[3][3];
#pragma unroll
            for (int s = 0; s < 3; ++s)
#pragma unroll
                for (int r = 0; r < 3; ++r) {
                    float v = w[s] + w[3 + r] - 2.0f * w[6 + s * 3 + r];
                    D[s][r] = sqrtf(fmaxf(v, 0.0f));
                }
#pragma unroll
            for (int p = 0; p < 6; ++p) {
                float su = (D[0][perms[p][0]] + D[1][perms[p][1]] +
                            D[2][perms[p][2]]) * (1.0f / 3.0f);
                accp[p] += fabsf(su);
            }
        }
        float mn = 3.0e38f;
#pragma unroll
        for (int p = 0; p < 6; ++p) {
            float loss = accp[p] * (1.0f / (float)B_DIM);
            mn = fminf(mn, loss);
        }
        out[0] = logf(mn);
    }
}

extern "C" void kernel_launch(void* const* d_in, const int* in_sizes, int n_in,
                              void* d_out, int out_size, void* d_ws, size_t ws_size,
                              hipStream_t stream) {
    const float* P = (const float*)d_in[0];
    const float* G = (const float*)d_in[1];
    float* out = (float*)d_out;
    float* ws  = (float*)d_ws;

    minloss_partial<<<B_DIM * BLOCKS_PER_B, 256, 0, stream>>>(P, G, ws);
    minloss_finalize<<<1, 256, 0, stream>>>(ws, out);
}